// Round 10
// baseline (135.109 us; speedup 1.0000x reference)
//
#include <hip/hip_runtime.h>

// MoE: out[b,:] = sum_e softmax(gate(x))[b,e] * (W3_e^T @ relu(W2_e^T @ relu(W1_e^T @ x_b + b1) + b2) + b3)
// R18: R17 (32x32x16 MFMA, 32 tokens/tile, layout HW-verified absmax 0.0156) + TB=2 tile
//      interleave. Accounting across R12-R17: MFMA pipe cost is invariant ~41 cyc/token
//      (matches MfmaUtil~30% in both shapes); wall ~134-141 cyc/token = 3.3x that floor;
//      TLP saturates at 2-3 waves; ILP-widening and load-pipelining were null. Dominant
//      residual: per-tile dependent chains (worst: Y = 16 serially dependent MFMAs; plus
//      MFMA->pack->MFMA per layer) at 2 resident waves. Fix: TWO tiles interleaved per
//      expert iteration (R13's proven latency-hider) -- tile B's chain fills tile A's stalls.
//      Paid for by: G1/G2/bg2 -> LDS w/ volatile per-iter reads (R15 trick) and b3 folded
//      into Y C-INIT (Y row r == b3[(r&3)+8(r>>2)+4h] because L3 rows are m=2e+o; kills
//      b3P regs AND 8 epilogue adds). waves_per_eu(2,2): proven 128 arch + 128 acc cap.
//      512 blocks x 4 waves = 2048 waves x 16 tiles (8 iters of 2), zero tail.
//      Falsifiable: absmax <= 0.0156; WRITE_SIZE stays 8.19 MB; VGPR <= 128.

typedef _Float16 half2_t __attribute__((ext_vector_type(2)));
typedef _Float16 half8_t __attribute__((ext_vector_type(8)));
typedef __fp16   fp16v2  __attribute__((ext_vector_type(2)));
typedef float  f32x16   __attribute__((ext_vector_type(16)));
typedef float  float4_t __attribute__((ext_vector_type(4)));
typedef float  float2_t __attribute__((ext_vector_type(2)));
typedef int    int4_t   __attribute__((ext_vector_type(4)));

#define MFMA32(A, B, C) __builtin_amdgcn_mfma_f32_32x32x16_f16((A), (B), (C), 0, 0, 0)

static constexpr int E_ = 8, DIN_ = 6, H_ = 32, TB_ = 2;

union H8U { half2_t h2[4]; half8_t h8; int4_t i4; };
union HI  { half2_t h; int i; };
union PKU { fp16v2 p; half2_t h; };
union C16 { f32x16 v; float4_t q[4]; };

__device__ __forceinline__ half2_t pkrtz(float a, float b) {
    PKU u; u.p = __builtin_amdgcn_cvt_pkrtz(a, b);
    return u.h;
}

__device__ __forceinline__ half2_t relu2(half2_t v) {
    const half2_t z = {(_Float16)0.0f, (_Float16)0.0f};
    return __builtin_elementwise_max(v, z);
}

__global__ __launch_bounds__(256)
__attribute__((amdgpu_waves_per_eu(2, 2)))
void moe_kernel(
    const float* __restrict__ x,  const float* __restrict__ W1, const float* __restrict__ b1,
    const float* __restrict__ W2, const float* __restrict__ b2, const float* __restrict__ W3,
    const float* __restrict__ b3, const float* __restrict__ Wg1, const float* __restrict__ bg1,
    const float* __restrict__ Wg2, const float* __restrict__ bg2,
    float* __restrict__ out, int nTok, int nTiles, int tilesPerWave)
{
    const int tid  = threadIdx.x;
    const int lane = tid & 63;
    const int m    = lane & 31;   // A-row / token-column index
    const int h    = lane >> 5;   // lane half: K sub-block selector
    const int wv   = tid >> 6;    // wave in block
    const int gw   = (blockIdx.x << 2) + wv;   // global wave id (waves independent)

    // block-uniform weight images (pi-free 32x32 layouts)
    __shared__ H8U w1img[E_][64];        //  8 KB: L1 A-frag (k=features, bias at k=6)
    __shared__ H8U w2img[E_][2][64];     // 16 KB: L2 A-frag, K-blocks lo/hi
    __shared__ H8U a3img[E_][2][64];     // 16 KB: L3 A-frag, block-diag rows m=2e+o, zeros baked
    __shared__ __align__(16) float b2s[E_][H_];   // 1 KB: b2 rows (f32 C-init)
    __shared__ H8U g1s[64];              //  1 KB: gate L1 A-frag
    __shared__ H8U g2s[2][64];           //  2 KB: gate L2 A-frag, K-blocks
    __shared__ __align__(16) float b3s[16];       // b3 rows (Y C-init; row index == b3 index)
    __shared__ __align__(16) float bg2s[8];       // bg2 * log2e (gate C-init rows 0..7)

    const float L2E = 1.44269504f;
    const half2_t h2z = pkrtz(0.f, 0.f);

    // ---- build expert images: wave wv packs experts {2wv, 2wv+1} (layout verified in R17)
    #pragma unroll
    for (int j = 0; j < 2; ++j) {
        const int e = wv * 2 + j;
        H8U w1v;
        if (h == 0) {
            w1v.h2[0] = pkrtz(W1[(e*DIN_+0)*H_+m], W1[(e*DIN_+1)*H_+m]);
            w1v.h2[1] = pkrtz(W1[(e*DIN_+2)*H_+m], W1[(e*DIN_+3)*H_+m]);
        } else {
            w1v.h2[0] = pkrtz(W1[(e*DIN_+4)*H_+m], W1[(e*DIN_+5)*H_+m]);
            w1v.h2[1] = pkrtz(b1[e*H_+m], 0.f);          // k=6 bias slot; k=7 zero
        }
        w1v.h2[2] = h2z; w1v.h2[3] = h2z;                // k>=8 zero
        w1img[e][lane] = w1v;

        const int o = m & 1;
        const bool alive = ((m >> 1) == e);              // rows m=2e+o only (m<16)
        #pragma unroll
        for (int b = 0; b < 2; ++b) {
            H8U w2v, a3v;
            #pragma unroll
            for (int p = 0; p < 4; ++p) {
                const int k0 = 16*b + 8*(p>>1) + 4*h + 2*(p&1);
                w2v.h2[p] = pkrtz(W2[(e*H_+k0)*H_+m], W2[(e*H_+k0+1)*H_+m]);
                a3v.h2[p] = alive ? pkrtz(W3[(e*H_+k0)*2+o], W3[(e*H_+k0+1)*2+o]) : h2z;
            }
            w2img[e][b][lane] = w2v;
            a3img[e][b][lane] = a3v;
        }
        if (lane < H_) b2s[e][lane] = b2[e*H_ + lane];
    }

    // ---- wave 0 builds gate images + bias tables
    if (wv == 0) {
        H8U g1v;
        if (h == 0) {
            g1v.h2[0] = pkrtz(Wg1[0*H_+m], Wg1[1*H_+m]);
            g1v.h2[1] = pkrtz(Wg1[2*H_+m], Wg1[3*H_+m]);
        } else {
            g1v.h2[0] = pkrtz(Wg1[4*H_+m], Wg1[5*H_+m]);
            g1v.h2[1] = pkrtz(bg1[m], 0.f);
        }
        g1v.h2[2] = h2z; g1v.h2[3] = h2z;
        g1s[lane] = g1v;

        const bool alive = (m < E_);                     // logits rows 0..7 only
        #pragma unroll
        for (int b = 0; b < 2; ++b) {
            H8U g2v;
            #pragma unroll
            for (int p = 0; p < 4; ++p) {
                const int k0 = 16*b + 8*(p>>1) + 4*h + 2*(p&1);
                g2v.h2[p] = alive ? pkrtz(Wg2[k0*E_+m]*L2E, Wg2[(k0+1)*E_+m]*L2E) : h2z;
            }
            g2s[b][lane] = g2v;
        }
        if (lane < 16) b3s[lane] = b3[lane];
        if (lane < E_) bg2s[lane] = bg2[lane] * L2E;
    }

    const f32x16 z16 = {0,0,0,0, 0,0,0,0, 0,0,0,0, 0,0,0,0};
    const float4_t z4 = {0.f, 0.f, 0.f, 0.f};

    __syncthreads();   // images ready; NO barriers inside the loop

    const int tile0 = gw * tilesPerWave;
    const int xo1 = h ? 4 : 0;
    const int xo2 = h ? 4 : 2;
    const float* xq = x + ((size_t)tile0 * 32 + m) * DIN_;
    float2_t la[TB_], lb[TB_];
    #pragma unroll
    for (int u = 0; u < TB_; ++u) {
        la[u] = float2_t{0.f, 0.f};
        lb[u] = float2_t{0.f, 0.f};
        if (tile0 + u < nTiles && (size_t)(tile0 + u) * 32 + m < (size_t)nTok) {
            la[u] = *(const float2_t*)(xq + (size_t)u * 32 * DIN_ + xo1);
            lb[u] = *(const float2_t*)(xq + (size_t)u * 32 * DIN_ + xo2);
        }
    }
    HI onei; onei.h = pkrtz(1.f, 0.f);

    // ---- main loop: TWO 32-token tiles per iteration, interleaved per expert
    for (int it = 0; it < tilesPerWave; it += TB_) {
        const int tbase = tile0 + it;
        if (tbase >= nTiles) break;         // uniform per wave

        // per-iter volatile reads (must not be hoisted into persistent registers)
        H8U g1v;  g1v.i4  = *(const volatile int4_t*)&g1s[lane].i4;
        H8U g2v0; g2v0.i4 = *(const volatile int4_t*)&g2s[0][lane].i4;
        H8U g2v1; g2v1.i4 = *(const volatile int4_t*)&g2s[1][lane].i4;
        float4_t bgq  = *(const volatile float4_t*)&bg2s[4*h];
        float4_t b3q0 = *(const volatile float4_t*)&b3s[4*h];        // Y regs 0-3 rows 4h+r
        float4_t b3q1 = *(const volatile float4_t*)&b3s[8 + 4*h];    // Y regs 4-7 rows 8+4h+r

        // x B-frags: h=0: {x0..x3, 0..}; h=1: {x4,x5,1,0, 0..}
        H8U xB[TB_];
        #pragma unroll
        for (int u = 0; u < TB_; ++u) {
            xB[u].h2[0] = pkrtz(la[u][0], la[u][1]);
            HI hb; hb.h = pkrtz(lb[u][0], lb[u][1]);
            HI se; se.i = h ? onei.i : hb.i;
            xB[u].h2[1] = se.h;
            xB[u].h2[2] = h2z; xB[u].h2[3] = h2z;
        }

        // prefetch next pair's x
        if (it + TB_ < tilesPerWave) {
            const float* xn = xq + (size_t)(it + TB_) * 32 * DIN_;
            #pragma unroll
            for (int u = 0; u < TB_; ++u) {
                if (tbase + TB_ + u < nTiles &&
                    (size_t)(tbase + TB_ + u) * 32 + m < (size_t)nTok) {
                    la[u] = *(const float2_t*)(xn + (size_t)u * 32 * DIN_ + xo1);
                    lb[u] = *(const float2_t*)(xn + (size_t)u * 32 * DIN_ + xo2);
                }
            }
        }

        // ---- gates (two independent chains; logits rows 4h+0..3 = experts 4h+0..3)
        float wA[TB_], wB[TB_], wC[TB_], wD[TB_], rs[TB_];
        #pragma unroll
        for (int u = 0; u < TB_; ++u) {
            f32x16 hg = MFMA32(g1v.h8, xB[u].h8, z16);
            H8U uhlo, uhhi;
            #pragma unroll
            for (int i = 0; i < 4; ++i) {
                uhlo.h2[i] = relu2(pkrtz(hg[2*i],   hg[2*i+1]));
                uhhi.h2[i] = relu2(pkrtz(hg[8+2*i], hg[8+2*i+1]));
            }
            C16 gc; gc.q[0] = bgq; gc.q[1] = z4; gc.q[2] = z4; gc.q[3] = z4;
            f32x16 gl = MFMA32(g2v0.h8, uhlo.h8, gc.v);
            gl = MFMA32(g2v1.h8, uhhi.h8, gl);

            float ex0 = __builtin_amdgcn_exp2f(gl[0]);
            float ex1 = __builtin_amdgcn_exp2f(gl[1]);
            float ex2 = __builtin_amdgcn_exp2f(gl[2]);
            float ex3 = __builtin_amdgcn_exp2f(gl[3]);
            float s = (ex0 + ex1) + (ex2 + ex3);
            s += __shfl_xor(s, 32);
            rs[u] = __builtin_amdgcn_rcpf(s);
            float sA = h ? ex0 : ex2, sB = h ? ex1 : ex3;
            HI sp; sp.h = pkrtz(sA, sB);
            HI rp; rp.i = __shfl_xor(sp.i, 32);
            float rA = (float)rp.h[0], rB = (float)rp.h[1];
            wA[u] = h ? rA : ex0; wB[u] = h ? rB : ex1;
            wC[u] = h ? ex2 : rA; wD[u] = h ? ex3 : rB;
        }

        // ---- all 8 experts x 2 tiles; Y C-init carries b3 (regs 0-7), rows>=16 zero
        f32x16 Y[TB_];
        #pragma unroll
        for (int u = 0; u < TB_; ++u) {
            C16 yc; yc.q[0] = b3q0; yc.q[1] = b3q1; yc.q[2] = z4; yc.q[3] = z4;
            Y[u] = yc.v;
        }
        #pragma unroll
        for (int e = 0; e < E_; ++e) {
            H8U a1;   a1.i4   = w1img[e][lane].i4;
            H8U a2lo; a2lo.i4 = w2img[e][0][lane].i4;
            H8U a2hi; a2hi.i4 = w2img[e][1][lane].i4;
            H8U a3lo; a3lo.i4 = a3img[e][0][lane].i4;
            H8U a3hi; a3hi.i4 = a3img[e][1][lane].i4;
            C16 bc;
            bc.q[0] = *(const float4_t*)&b2s[e][4*h];
            bc.q[1] = *(const float4_t*)&b2s[e][8 + 4*h];
            bc.q[2] = *(const float4_t*)&b2s[e][16 + 4*h];
            bc.q[3] = *(const float4_t*)&b2s[e][24 + 4*h];

            #pragma unroll
            for (int u = 0; u < TB_; ++u) {
                f32x16 c1 = MFMA32(a1.h8, xB[u].h8, z16);
                H8U u1lo, u1hi;
                #pragma unroll
                for (int i = 0; i < 4; ++i) {
                    u1lo.h2[i] = relu2(pkrtz(c1[2*i],   c1[2*i+1]));
                    u1hi.h2[i] = relu2(pkrtz(c1[8+2*i], c1[8+2*i+1]));
                }
                f32x16 c2 = MFMA32(a2lo.h8, u1lo.h8, bc.v);     // b2 in f32 C-init
                c2 = MFMA32(a2hi.h8, u1hi.h8, c2);
                H8U u2lo, u2hi;
                #pragma unroll
                for (int i = 0; i < 4; ++i) {
                    u2lo.h2[i] = relu2(pkrtz(c2[2*i],   c2[2*i+1]));
                    u2hi.h2[i] = relu2(pkrtz(c2[8+2*i], c2[8+2*i+1]));
                }
                Y[u] = MFMA32(a3lo.h8, u2lo.h8, Y[u]);
                Y[u] = MFMA32(a3hi.h8, u2hi.h8, Y[u]);
            }
        }

        // ---- epilogues: Y regs 0-7 = rows {4h..4h+3, 8+4h..+3} = (e,o); b3 already inside
        #pragma unroll
        for (int u = 0; u < TB_; ++u) {
            const int tile = tbase + u;
            float p0 = wA[u]*Y[u][0] + wB[u]*Y[u][2] + wC[u]*Y[u][4] + wD[u]*Y[u][6];
            float p1 = wA[u]*Y[u][1] + wB[u]*Y[u][3] + wC[u]*Y[u][5] + wD[u]*Y[u][7];
            p0 += __shfl_xor(p0, 32);
            p1 += __shfl_xor(p1, 32);
            const bool tok = tile < nTiles && ((size_t)tile * 32 + m) < (size_t)nTok;
            if (h == 0 && tok) {
                float2_t ov = {p0 * rs[u], p1 * rs[u]};
                *(float2_t*)(out + ((size_t)tile * 32 + m) * 2) = ov;
            }
        }
    }
}

extern "C" void kernel_launch(void* const* d_in, const int* in_sizes, int n_in,
                              void* d_out, int out_size, void* d_ws, size_t ws_size,
                              hipStream_t stream) {
    const float* x   = (const float*)d_in[0];
    const float* W1  = (const float*)d_in[1];
    const float* b1  = (const float*)d_in[2];
    const float* W2  = (const float*)d_in[3];
    const float* b2  = (const float*)d_in[4];
    const float* W3  = (const float*)d_in[5];
    const float* b3  = (const float*)d_in[6];
    const float* Wg1 = (const float*)d_in[7];
    const float* bg1 = (const float*)d_in[8];
    const float* Wg2 = (const float*)d_in[9];
    const float* bg2 = (const float*)d_in[10];
    float* out = (float*)d_out;

    const int B      = in_sizes[0] / DIN_;
    const int nTiles = (B + 31) / 32;
    // waves_per_eu(2,2): 128 arch + 128 acc (proven). 512 blocks x 4 waves = 2048 waves =
    // exact 2 waves/SIMD; ~45 KB LDS x 2 blocks/CU <= 160 KB. 32768 tiles / 2048 waves =
    // 16 tiles/wave = 8 iterations of 2, zero tail at B=1M.
    const int blocks = 512;
    const int wavesTotal = blocks * 4;
    const int tpw = (nTiles + wavesTotal - 1) / wavesTotal;

    moe_kernel<<<blocks, 256, 0, stream>>>(x, W1, b1, W2, b2, W3, b3,
                                           Wg1, bg1, Wg2, bg2, out, B, nTiles, tpw);
}

// Round 11
// 131.195 us; speedup vs baseline: 1.0298x; 1.0298x over previous
//
#include <hip/hip_runtime.h>

// MoE: out[b,:] = sum_e softmax(gate(x))[b,e] * (W3_e^T @ relu(W2_e^T @ relu(W1_e^T @ x_b + b1) + b2) + b3)
// R19: 32x32x16 base (R17 layout, HW-verified absmax 0.0156) at THREE waves/SIMD.
//      Ladder evidence: 1->2 waves = 1.95x; 16x16 at 3 waves = +9% only; ILP/pipelining/tile
//      levers all null; three different kernels all land 56-60 us with reported VALUBusy
//      35-48%. Hypothesis: gfx94x-formula counters under-report ~2x on SIMD-32 gfx950 =>
//      16x16 kernels were VALU-SATURATED (~90-95% true) at >=2 waves -- which explains every
//      null. The 32x32 base halves VALU/token (true ~75% at 2 waves) => it alone has headroom
//      for a 3rd wave. TB=1 (R18 proved TB2==TB1; -12-16 arch regs => ~75 <= 85 cap of
//      waves_per_eu(3,3) under the proven even arch/acc split). Gate/bias images in LDS with
//      per-iter volatile reads (R15 trick). 768 blocks x 4 waves = 3 blocks/CU = 3 waves/SIMD,
//      132 KB LDS/CU. Falsifiable: VGPR <= 85 & WRITE_SIZE stays 8.19 MB (no spills);
//      absmax <= 0.0156; dur 58 -> ~45-50 us. Null => declare structural floor.

typedef _Float16 half2_t __attribute__((ext_vector_type(2)));
typedef _Float16 half8_t __attribute__((ext_vector_type(8)));
typedef __fp16   fp16v2  __attribute__((ext_vector_type(2)));
typedef float  f32x16   __attribute__((ext_vector_type(16)));
typedef float  float4_t __attribute__((ext_vector_type(4)));
typedef float  float2_t __attribute__((ext_vector_type(2)));
typedef int    int4_t   __attribute__((ext_vector_type(4)));

#define MFMA32(A, B, C) __builtin_amdgcn_mfma_f32_32x32x16_f16((A), (B), (C), 0, 0, 0)

static constexpr int E_ = 8, DIN_ = 6, H_ = 32;

union H8U { half2_t h2[4]; half8_t h8; int4_t i4; };
union HI  { half2_t h; int i; };
union PKU { fp16v2 p; half2_t h; };
union C16 { f32x16 v; float4_t q[4]; };

__device__ __forceinline__ half2_t pkrtz(float a, float b) {
    PKU u; u.p = __builtin_amdgcn_cvt_pkrtz(a, b);
    return u.h;
}

__device__ __forceinline__ half2_t relu2(half2_t v) {
    const half2_t z = {(_Float16)0.0f, (_Float16)0.0f};
    return __builtin_elementwise_max(v, z);
}

__global__ __launch_bounds__(256)
__attribute__((amdgpu_waves_per_eu(3, 3)))
void moe_kernel(
    const float* __restrict__ x,  const float* __restrict__ W1, const float* __restrict__ b1,
    const float* __restrict__ W2, const float* __restrict__ b2, const float* __restrict__ W3,
    const float* __restrict__ b3, const float* __restrict__ Wg1, const float* __restrict__ bg1,
    const float* __restrict__ Wg2, const float* __restrict__ bg2,
    float* __restrict__ out, int nTok, int nTiles, int tilesPerWave)
{
    const int tid  = threadIdx.x;
    const int lane = tid & 63;
    const int m    = lane & 31;   // A-row / token-column index
    const int h    = lane >> 5;   // lane half: K sub-block selector
    const int wv   = tid >> 6;    // wave in block
    const int gw   = (blockIdx.x << 2) + wv;   // global wave id (waves independent)

    // block-uniform weight images (pi-free 32x32 layouts, verified R17)
    __shared__ H8U w1img[E_][64];        //  8 KB: L1 A-frag (k=features, bias at k=6)
    __shared__ H8U w2img[E_][2][64];     // 16 KB: L2 A-frag, K-blocks lo/hi
    __shared__ H8U a3img[E_][2][64];     // 16 KB: L3 A-frag, block-diag rows m=2e+o, zeros baked
    __shared__ __align__(16) float b2s[E_][H_];   // 1 KB: b2 rows (f32 C-init)
    __shared__ H8U g1s[64];              //  1 KB: gate L1 A-frag
    __shared__ H8U g2s[2][64];           //  2 KB: gate L2 A-frag, K-blocks
    __shared__ __align__(16) float b3s[16];       // b3 rows (Y C-init; row index == b3 index)
    __shared__ __align__(16) float bg2s[8];       // bg2 * log2e (gate C-init rows 0..7)

    const float L2E = 1.44269504f;
    const half2_t h2z = pkrtz(0.f, 0.f);

    // ---- build expert images: wave wv packs experts {2wv, 2wv+1}
    #pragma unroll
    for (int j = 0; j < 2; ++j) {
        const int e = wv * 2 + j;
        H8U w1v;
        if (h == 0) {
            w1v.h2[0] = pkrtz(W1[(e*DIN_+0)*H_+m], W1[(e*DIN_+1)*H_+m]);
            w1v.h2[1] = pkrtz(W1[(e*DIN_+2)*H_+m], W1[(e*DIN_+3)*H_+m]);
        } else {
            w1v.h2[0] = pkrtz(W1[(e*DIN_+4)*H_+m], W1[(e*DIN_+5)*H_+m]);
            w1v.h2[1] = pkrtz(b1[e*H_+m], 0.f);          // k=6 bias slot; k=7 zero
        }
        w1v.h2[2] = h2z; w1v.h2[3] = h2z;                // k>=8 zero
        w1img[e][lane] = w1v;

        const int o = m & 1;
        const bool alive = ((m >> 1) == e);              // rows m=2e+o only (m<16)
        #pragma unroll
        for (int b = 0; b < 2; ++b) {
            H8U w2v, a3v;
            #pragma unroll
            for (int p = 0; p < 4; ++p) {
                const int k0 = 16*b + 8*(p>>1) + 4*h + 2*(p&1);
                w2v.h2[p] = pkrtz(W2[(e*H_+k0)*H_+m], W2[(e*H_+k0+1)*H_+m]);
                a3v.h2[p] = alive ? pkrtz(W3[(e*H_+k0)*2+o], W3[(e*H_+k0+1)*2+o]) : h2z;
            }
            w2img[e][b][lane] = w2v;
            a3img[e][b][lane] = a3v;
        }
        if (lane < H_) b2s[e][lane] = b2[e*H_ + lane];
    }

    // ---- wave 0 builds gate images + bias tables
    if (wv == 0) {
        H8U g1v;
        if (h == 0) {
            g1v.h2[0] = pkrtz(Wg1[0*H_+m], Wg1[1*H_+m]);
            g1v.h2[1] = pkrtz(Wg1[2*H_+m], Wg1[3*H_+m]);
        } else {
            g1v.h2[0] = pkrtz(Wg1[4*H_+m], Wg1[5*H_+m]);
            g1v.h2[1] = pkrtz(bg1[m], 0.f);
        }
        g1v.h2[2] = h2z; g1v.h2[3] = h2z;
        g1s[lane] = g1v;

        const bool alive = (m < E_);                     // logits rows 0..7 only
        #pragma unroll
        for (int b = 0; b < 2; ++b) {
            H8U g2v;
            #pragma unroll
            for (int p = 0; p < 4; ++p) {
                const int k0 = 16*b + 8*(p>>1) + 4*h + 2*(p&1);
                g2v.h2[p] = alive ? pkrtz(Wg2[k0*E_+m]*L2E, Wg2[(k0+1)*E_+m]*L2E) : h2z;
            }
            g2s[b][lane] = g2v;
        }
        if (lane < 16) b3s[lane] = b3[lane];
        if (lane < E_) bg2s[lane] = bg2[lane] * L2E;
    }

    const f32x16 z16 = {0,0,0,0, 0,0,0,0, 0,0,0,0, 0,0,0,0};
    const float4_t z4 = {0.f, 0.f, 0.f, 0.f};

    __syncthreads();   // images ready; NO barriers inside the loop

    const int tile0 = gw * tilesPerWave;
    const int xo1 = h ? 4 : 0;
    const int xo2 = h ? 4 : 2;
    const float* xq = x + ((size_t)tile0 * 32 + m) * DIN_;
    float2_t la = {0.f, 0.f}, lb = {0.f, 0.f};
    if (tile0 < nTiles && (size_t)tile0 * 32 + m < (size_t)nTok) {
        la = *(const float2_t*)(xq + xo1);
        lb = *(const float2_t*)(xq + xo2);
    }
    HI onei; onei.h = pkrtz(1.f, 0.f);

    // ---- main loop: one 32-token tile per iteration (TB=1; R18 proved TB2==TB1)
    for (int it = 0; it < tilesPerWave; ++it) {
        const int tile = tile0 + it;
        if (tile >= nTiles) break;          // uniform per wave
        const bool tok = ((size_t)tile * 32 + m) < (size_t)nTok;

        // per-iter volatile reads (must not be hoisted into persistent registers)
        H8U g1v;  g1v.i4  = *(const volatile int4_t*)&g1s[lane].i4;
        H8U g2v0; g2v0.i4 = *(const volatile int4_t*)&g2s[0][lane].i4;
        H8U g2v1; g2v1.i4 = *(const volatile int4_t*)&g2s[1][lane].i4;
        float4_t bgq  = *(const volatile float4_t*)&bg2s[4*h];
        float4_t b3q0 = *(const volatile float4_t*)&b3s[4*h];        // Y regs 0-3 rows 4h+r
        float4_t b3q1 = *(const volatile float4_t*)&b3s[8 + 4*h];    // Y regs 4-7 rows 8+4h+r

        // x B-frag: h=0: {x0..x3, 0..}; h=1: {x4,x5,1,0, 0..}
        H8U xB;
        xB.h2[0] = pkrtz(la[0], la[1]);
        { HI hb; hb.h = pkrtz(lb[0], lb[1]); HI se; se.i = h ? onei.i : hb.i; xB.h2[1] = se.h; }
        xB.h2[2] = h2z; xB.h2[3] = h2z;

        // prefetch next tile's x
        if (it + 1 < tilesPerWave && tile + 1 < nTiles) {
            const float* xn = xq + (size_t)(it + 1) * 32 * DIN_;
            if ((size_t)(tile + 1) * 32 + m < (size_t)nTok) {
                la = *(const float2_t*)(xn + xo1);
                lb = *(const float2_t*)(xn + xo2);
            }
        }

        // ---- gate: 3 MFMAs; logits rows 4h+0..3 = experts 4h+0..3
        f32x16 hg = MFMA32(g1v.h8, xB.h8, z16);
        H8U uhlo, uhhi;
        #pragma unroll
        for (int i = 0; i < 4; ++i) {
            uhlo.h2[i] = relu2(pkrtz(hg[2*i],   hg[2*i+1]));
            uhhi.h2[i] = relu2(pkrtz(hg[8+2*i], hg[8+2*i+1]));
        }
        C16 gc; gc.q[0] = bgq; gc.q[1] = z4; gc.q[2] = z4; gc.q[3] = z4;
        f32x16 gl = MFMA32(g2v0.h8, uhlo.h8, gc.v);
        gl = MFMA32(g2v1.h8, uhhi.h8, gl);

        // softmax over 8 experts (log2 domain; no max-sub), normalization deferred
        float ex0 = __builtin_amdgcn_exp2f(gl[0]);
        float ex1 = __builtin_amdgcn_exp2f(gl[1]);
        float ex2 = __builtin_amdgcn_exp2f(gl[2]);
        float ex3 = __builtin_amdgcn_exp2f(gl[3]);
        float s = (ex0 + ex1) + (ex2 + ex3);
        s += __shfl_xor(s, 32);
        float rs = __builtin_amdgcn_rcpf(s);
        float sA = h ? ex0 : ex2, sB = h ? ex1 : ex3;
        HI sp; sp.h = pkrtz(sA, sB);
        HI rp; rp.i = __shfl_xor(sp.i, 32);
        float rA = (float)rp.h[0], rB = (float)rp.h[1];
        float wA = h ? rA : ex0, wB = h ? rB : ex1;
        float wC = h ? ex2 : rA, wD = h ? ex3 : rB;

        // ---- all 8 experts: 5 MFMAs each; Y C-init carries b3 (regs 0-7), rows>=16 zero
        f32x16 Y;
        { C16 yc; yc.q[0] = b3q0; yc.q[1] = b3q1; yc.q[2] = z4; yc.q[3] = z4; Y = yc.v; }
        #pragma unroll
        for (int e = 0; e < E_; ++e) {
            H8U a1;   a1.i4   = w1img[e][lane].i4;
            H8U a2lo; a2lo.i4 = w2img[e][0][lane].i4;
            H8U a2hi; a2hi.i4 = w2img[e][1][lane].i4;
            H8U a3lo; a3lo.i4 = a3img[e][0][lane].i4;
            H8U a3hi; a3hi.i4 = a3img[e][1][lane].i4;
            C16 bc;
            bc.q[0] = *(const float4_t*)&b2s[e][4*h];
            bc.q[1] = *(const float4_t*)&b2s[e][8 + 4*h];
            bc.q[2] = *(const float4_t*)&b2s[e][16 + 4*h];
            bc.q[3] = *(const float4_t*)&b2s[e][24 + 4*h];

            f32x16 c1 = MFMA32(a1.h8, xB.h8, z16);
            H8U u1lo, u1hi;
            #pragma unroll
            for (int i = 0; i < 4; ++i) {
                u1lo.h2[i] = relu2(pkrtz(c1[2*i],   c1[2*i+1]));
                u1hi.h2[i] = relu2(pkrtz(c1[8+2*i], c1[8+2*i+1]));
            }
            f32x16 c2 = MFMA32(a2lo.h8, u1lo.h8, bc.v);     // b2 in f32 C-init
            c2 = MFMA32(a2hi.h8, u1hi.h8, c2);
            H8U u2lo, u2hi;
            #pragma unroll
            for (int i = 0; i < 4; ++i) {
                u2lo.h2[i] = relu2(pkrtz(c2[2*i],   c2[2*i+1]));
                u2hi.h2[i] = relu2(pkrtz(c2[8+2*i], c2[8+2*i+1]));
            }
            Y = MFMA32(a3lo.h8, u2lo.h8, Y);
            Y = MFMA32(a3hi.h8, u2hi.h8, Y);
        }

        // ---- epilogue: Y regs 0-7 = rows {4h..4h+3, 8+4h..+3} = (e,o); b3 already inside
        float p0 = wA*Y[0] + wB*Y[2] + wC*Y[4] + wD*Y[6];
        float p1 = wA*Y[1] + wB*Y[3] + wC*Y[5] + wD*Y[7];
        p0 += __shfl_xor(p0, 32);
        p1 += __shfl_xor(p1, 32);
        if (h == 0 && tok) {
            float2_t ov = {p0 * rs, p1 * rs};
            *(float2_t*)(out + ((size_t)tile * 32 + m) * 2) = ov;
        }
    }
}

extern "C" void kernel_launch(void* const* d_in, const int* in_sizes, int n_in,
                              void* d_out, int out_size, void* d_ws, size_t ws_size,
                              hipStream_t stream) {
    const float* x   = (const float*)d_in[0];
    const float* W1  = (const float*)d_in[1];
    const float* b1  = (const float*)d_in[2];
    const float* W2  = (const float*)d_in[3];
    const float* b2  = (const float*)d_in[4];
    const float* W3  = (const float*)d_in[5];
    const float* b3  = (const float*)d_in[6];
    const float* Wg1 = (const float*)d_in[7];
    const float* bg1 = (const float*)d_in[8];
    const float* Wg2 = (const float*)d_in[9];
    const float* bg2 = (const float*)d_in[10];
    float* out = (float*)d_out;

    const int B      = in_sizes[0] / DIN_;
    const int nTiles = (B + 31) / 32;
    // waves_per_eu(3,3): arch ~85 + acc ~85 (proven even split). 768 blocks x 4 waves =
    // 3072 waves = exact 3 blocks/CU (3 waves/SIMD), 132 KB LDS/CU. tpw = ceil(32768/3072)
    // = 11; ragged tail via per-tile guards.
    const int blocks = 768;
    const int wavesTotal = blocks * 4;
    const int tpw = (nTiles + wavesTotal - 1) / wavesTotal;

    moe_kernel<<<blocks, 256, 0, stream>>>(x, W1, b1, W2, b2, W3, b3,
                                           Wg1, bg1, Wg2, bg2, out, B, nTiles, tpw);
}

// Round 12
// 128.886 us; speedup vs baseline: 1.0483x; 1.0179x over previous
//
#include <hip/hip_runtime.h>

// MoE: out[b,:] = sum_e softmax(gate(x))[b,e] * (W3_e^T @ relu(W2_e^T @ relu(W1_e^T @ x_b + b1) + b2) + b3)
// R20: R18 (32x32x16, TB=2, 2 waves/SIMD, layout verified) + T19 sched_group_barrier forced
//      interleave. Complete falsification ledger R12-R19: spills/TLP/ILP/LDS-lat/LDS-BW/VALU/
//      HBM/banks/issue all ruled out; corrected MFMA model (32x32x16 = ~32 SIMD-cyc) shows
//      MfmaUtil 31% is ACCURATE -> wall = 3.2x the MFMA floor with nothing saturated.
//      Surviving theory: dependent MFMA->pack->MFMA chain latency with the compiler emitting
//      the two independent tile-chains SERIALLY (register-pressure-min order), so R14/R18's
//      source-level independence never reached the HW. Fix: per-expert sched_group_barrier
//      pattern {DS_READ 9 -> MFMA 2 (L1 A,B) -> VALU 32 -> MFMA 4 (L2) -> VALU 32 -> MFMA 4
//      (L3)} forces same-stage MFMAs of both tiles back-to-back (2-4 deep pipelining).
//      Prediction: mis-scheduling => 58 -> ~44-48 us, MfmaUtil -> 40%+; null => structural
//      floor, declare next round. Guards: WRITE_SIZE 8.19 MB, VGPR <= 128, absmax <= 0.0156.

typedef _Float16 half2_t __attribute__((ext_vector_type(2)));
typedef _Float16 half8_t __attribute__((ext_vector_type(8)));
typedef __fp16   fp16v2  __attribute__((ext_vector_type(2)));
typedef float  f32x16   __attribute__((ext_vector_type(16)));
typedef float  float4_t __attribute__((ext_vector_type(4)));
typedef float  float2_t __attribute__((ext_vector_type(2)));
typedef int    int4_t   __attribute__((ext_vector_type(4)));

#define MFMA32(A, B, C) __builtin_amdgcn_mfma_f32_32x32x16_f16((A), (B), (C), 0, 0, 0)
#define SGB __builtin_amdgcn_sched_group_barrier

static constexpr int E_ = 8, DIN_ = 6, H_ = 32, TB_ = 2;

union H8U { half2_t h2[4]; half8_t h8; int4_t i4; };
union HI  { half2_t h; int i; };
union PKU { fp16v2 p; half2_t h; };
union C16 { f32x16 v; float4_t q[4]; };

__device__ __forceinline__ half2_t pkrtz(float a, float b) {
    PKU u; u.p = __builtin_amdgcn_cvt_pkrtz(a, b);
    return u.h;
}

__device__ __forceinline__ half2_t relu2(half2_t v) {
    const half2_t z = {(_Float16)0.0f, (_Float16)0.0f};
    return __builtin_elementwise_max(v, z);
}

__global__ __launch_bounds__(256)
__attribute__((amdgpu_waves_per_eu(2, 2)))
void moe_kernel(
    const float* __restrict__ x,  const float* __restrict__ W1, const float* __restrict__ b1,
    const float* __restrict__ W2, const float* __restrict__ b2, const float* __restrict__ W3,
    const float* __restrict__ b3, const float* __restrict__ Wg1, const float* __restrict__ bg1,
    const float* __restrict__ Wg2, const float* __restrict__ bg2,
    float* __restrict__ out, int nTok, int nTiles, int tilesPerWave)
{
    const int tid  = threadIdx.x;
    const int lane = tid & 63;
    const int m    = lane & 31;   // A-row / token-column index
    const int h    = lane >> 5;   // lane half: K sub-block selector
    const int wv   = tid >> 6;    // wave in block
    const int gw   = (blockIdx.x << 2) + wv;   // global wave id (waves independent)

    __shared__ H8U w1img[E_][64];        //  8 KB: L1 A-frag (k=features, bias at k=6)
    __shared__ H8U w2img[E_][2][64];     // 16 KB: L2 A-frag, K-blocks lo/hi
    __shared__ H8U a3img[E_][2][64];     // 16 KB: L3 A-frag, block-diag rows m=2e+o, zeros baked
    __shared__ __align__(16) float b2s[E_][H_];   // 1 KB: b2 rows (f32 C-init)
    __shared__ H8U g1s[64];              //  1 KB: gate L1 A-frag
    __shared__ H8U g2s[2][64];           //  2 KB: gate L2 A-frag, K-blocks
    __shared__ __align__(16) float b3s[16];       // b3 rows (Y C-init; row index == b3 index)
    __shared__ __align__(16) float bg2s[8];       // bg2 * log2e (gate C-init rows 0..7)

    const float L2E = 1.44269504f;
    const half2_t h2z = pkrtz(0.f, 0.f);

    // ---- build expert images: wave wv packs experts {2wv, 2wv+1} (layout verified R17)
    #pragma unroll
    for (int j = 0; j < 2; ++j) {
        const int e = wv * 2 + j;
        H8U w1v;
        if (h == 0) {
            w1v.h2[0] = pkrtz(W1[(e*DIN_+0)*H_+m], W1[(e*DIN_+1)*H_+m]);
            w1v.h2[1] = pkrtz(W1[(e*DIN_+2)*H_+m], W1[(e*DIN_+3)*H_+m]);
        } else {
            w1v.h2[0] = pkrtz(W1[(e*DIN_+4)*H_+m], W1[(e*DIN_+5)*H_+m]);
            w1v.h2[1] = pkrtz(b1[e*H_+m], 0.f);          // k=6 bias slot; k=7 zero
        }
        w1v.h2[2] = h2z; w1v.h2[3] = h2z;                // k>=8 zero
        w1img[e][lane] = w1v;

        const int o = m & 1;
        const bool alive = ((m >> 1) == e);              // rows m=2e+o only (m<16)
        #pragma unroll
        for (int b = 0; b < 2; ++b) {
            H8U w2v, a3v;
            #pragma unroll
            for (int p = 0; p < 4; ++p) {
                const int k0 = 16*b + 8*(p>>1) + 4*h + 2*(p&1);
                w2v.h2[p] = pkrtz(W2[(e*H_+k0)*H_+m], W2[(e*H_+k0+1)*H_+m]);
                a3v.h2[p] = alive ? pkrtz(W3[(e*H_+k0)*2+o], W3[(e*H_+k0+1)*2+o]) : h2z;
            }
            w2img[e][b][lane] = w2v;
            a3img[e][b][lane] = a3v;
        }
        if (lane < H_) b2s[e][lane] = b2[e*H_ + lane];
    }

    // ---- wave 0 builds gate images + bias tables
    if (wv == 0) {
        H8U g1v;
        if (h == 0) {
            g1v.h2[0] = pkrtz(Wg1[0*H_+m], Wg1[1*H_+m]);
            g1v.h2[1] = pkrtz(Wg1[2*H_+m], Wg1[3*H_+m]);
        } else {
            g1v.h2[0] = pkrtz(Wg1[4*H_+m], Wg1[5*H_+m]);
            g1v.h2[1] = pkrtz(bg1[m], 0.f);
        }
        g1v.h2[2] = h2z; g1v.h2[3] = h2z;
        g1s[lane] = g1v;

        const bool alive = (m < E_);                     // logits rows 0..7 only
        #pragma unroll
        for (int b = 0; b < 2; ++b) {
            H8U g2v;
            #pragma unroll
            for (int p = 0; p < 4; ++p) {
                const int k0 = 16*b + 8*(p>>1) + 4*h + 2*(p&1);
                g2v.h2[p] = alive ? pkrtz(Wg2[k0*E_+m]*L2E, Wg2[(k0+1)*E_+m]*L2E) : h2z;
            }
            g2s[b][lane] = g2v;
        }
        if (lane < 16) b3s[lane] = b3[lane];
        if (lane < E_) bg2s[lane] = bg2[lane] * L2E;
    }

    const f32x16 z16 = {0,0,0,0, 0,0,0,0, 0,0,0,0, 0,0,0,0};
    const float4_t z4 = {0.f, 0.f, 0.f, 0.f};

    __syncthreads();   // images ready; NO barriers inside the loop

    const int tile0 = gw * tilesPerWave;
    const int xo1 = h ? 4 : 0;
    const int xo2 = h ? 4 : 2;
    const float* xq = x + ((size_t)tile0 * 32 + m) * DIN_;
    float2_t la[TB_], lb[TB_];
    #pragma unroll
    for (int u = 0; u < TB_; ++u) {
        la[u] = float2_t{0.f, 0.f};
        lb[u] = float2_t{0.f, 0.f};
        if (tile0 + u < nTiles && (size_t)(tile0 + u) * 32 + m < (size_t)nTok) {
            la[u] = *(const float2_t*)(xq + (size_t)u * 32 * DIN_ + xo1);
            lb[u] = *(const float2_t*)(xq + (size_t)u * 32 * DIN_ + xo2);
        }
    }
    HI onei; onei.h = pkrtz(1.f, 0.f);

    // ---- main loop: TWO 32-token tiles per iteration, interleave FORCED via SGB
    for (int it = 0; it < tilesPerWave; it += TB_) {
        const int tbase = tile0 + it;
        if (tbase >= nTiles) break;         // uniform per wave

        // per-iter volatile reads (must not be hoisted into persistent registers)
        H8U g1v;  g1v.i4  = *(const volatile int4_t*)&g1s[lane].i4;
        H8U g2v0; g2v0.i4 = *(const volatile int4_t*)&g2s[0][lane].i4;
        H8U g2v1; g2v1.i4 = *(const volatile int4_t*)&g2s[1][lane].i4;
        float4_t bgq  = *(const volatile float4_t*)&bg2s[4*h];
        float4_t b3q0 = *(const volatile float4_t*)&b3s[4*h];        // Y regs 0-3 rows 4h+r
        float4_t b3q1 = *(const volatile float4_t*)&b3s[8 + 4*h];    // Y regs 4-7 rows 8+4h+r

        // x B-frags: h=0: {x0..x3, 0..}; h=1: {x4,x5,1,0, 0..}
        H8U xB[TB_];
        #pragma unroll
        for (int u = 0; u < TB_; ++u) {
            xB[u].h2[0] = pkrtz(la[u][0], la[u][1]);
            HI hb; hb.h = pkrtz(lb[u][0], lb[u][1]);
            HI se; se.i = h ? onei.i : hb.i;
            xB[u].h2[1] = se.h;
            xB[u].h2[2] = h2z; xB[u].h2[3] = h2z;
        }

        // prefetch next pair's x
        if (it + TB_ < tilesPerWave) {
            const float* xn = xq + (size_t)(it + TB_) * 32 * DIN_;
            #pragma unroll
            for (int u = 0; u < TB_; ++u) {
                if (tbase + TB_ + u < nTiles &&
                    (size_t)(tbase + TB_ + u) * 32 + m < (size_t)nTok) {
                    la[u] = *(const float2_t*)(xn + (size_t)u * 32 * DIN_ + xo1);
                    lb[u] = *(const float2_t*)(xn + (size_t)u * 32 * DIN_ + xo2);
                }
            }
        }

        // ---- gates (two independent chains)
        float wA[TB_], wB[TB_], wC[TB_], wD[TB_], rs[TB_];
        #pragma unroll
        for (int u = 0; u < TB_; ++u) {
            f32x16 hg = MFMA32(g1v.h8, xB[u].h8, z16);
            H8U uhlo, uhhi;
            #pragma unroll
            for (int i = 0; i < 4; ++i) {
                uhlo.h2[i] = relu2(pkrtz(hg[2*i],   hg[2*i+1]));
                uhhi.h2[i] = relu2(pkrtz(hg[8+2*i], hg[8+2*i+1]));
            }
            C16 gc; gc.q[0] = bgq; gc.q[1] = z4; gc.q[2] = z4; gc.q[3] = z4;
            f32x16 gl = MFMA32(g2v0.h8, uhlo.h8, gc.v);
            gl = MFMA32(g2v1.h8, uhhi.h8, gl);

            float ex0 = __builtin_amdgcn_exp2f(gl[0]);
            float ex1 = __builtin_amdgcn_exp2f(gl[1]);
            float ex2 = __builtin_amdgcn_exp2f(gl[2]);
            float ex3 = __builtin_amdgcn_exp2f(gl[3]);
            float s = (ex0 + ex1) + (ex2 + ex3);
            s += __shfl_xor(s, 32);
            rs[u] = __builtin_amdgcn_rcpf(s);
            float sA = h ? ex0 : ex2, sB = h ? ex1 : ex3;
            HI sp; sp.h = pkrtz(sA, sB);
            HI rp; rp.i = __shfl_xor(sp.i, 32);
            float rA = (float)rp.h[0], rB = (float)rp.h[1];
            wA[u] = h ? rA : ex0; wB[u] = h ? rB : ex1;
            wC[u] = h ? ex2 : rA; wD[u] = h ? ex3 : rB;
        }

        // ---- all 8 experts x 2 tiles; interleave of the two independent chains FORCED
        f32x16 Y[TB_];
        #pragma unroll
        for (int u = 0; u < TB_; ++u) {
            C16 yc; yc.q[0] = b3q0; yc.q[1] = b3q1; yc.q[2] = z4; yc.q[3] = z4;
            Y[u] = yc.v;
        }
        #pragma unroll
        for (int e = 0; e < E_; ++e) {
            H8U a1;   a1.i4   = w1img[e][lane].i4;
            H8U a2lo; a2lo.i4 = w2img[e][0][lane].i4;
            H8U a2hi; a2hi.i4 = w2img[e][1][lane].i4;
            H8U a3lo; a3lo.i4 = a3img[e][0][lane].i4;
            H8U a3hi; a3hi.i4 = a3img[e][1][lane].i4;
            C16 bc;
            bc.q[0] = *(const float4_t*)&b2s[e][4*h];
            bc.q[1] = *(const float4_t*)&b2s[e][8 + 4*h];
            bc.q[2] = *(const float4_t*)&b2s[e][16 + 4*h];
            bc.q[3] = *(const float4_t*)&b2s[e][24 + 4*h];

            #pragma unroll
            for (int u = 0; u < TB_; ++u) {
                f32x16 c1 = MFMA32(a1.h8, xB[u].h8, z16);
                H8U u1lo, u1hi;
                #pragma unroll
                for (int i = 0; i < 4; ++i) {
                    u1lo.h2[i] = relu2(pkrtz(c1[2*i],   c1[2*i+1]));
                    u1hi.h2[i] = relu2(pkrtz(c1[8+2*i], c1[8+2*i+1]));
                }
                f32x16 c2 = MFMA32(a2lo.h8, u1lo.h8, bc.v);     // b2 in f32 C-init
                c2 = MFMA32(a2hi.h8, u1hi.h8, c2);
                H8U u2lo, u2hi;
                #pragma unroll
                for (int i = 0; i < 4; ++i) {
                    u2lo.h2[i] = relu2(pkrtz(c2[2*i],   c2[2*i+1]));
                    u2hi.h2[i] = relu2(pkrtz(c2[8+2*i], c2[8+2*i+1]));
                }
                Y[u] = MFMA32(a3lo.h8, u2lo.h8, Y[u]);
                Y[u] = MFMA32(a3hi.h8, u2hi.h8, Y[u]);
            }

            // T19: force the schedule for this expert: loads up front, then same-stage
            // MFMAs of the two independent tiles BACK-TO-BACK (2-4 deep pipelining),
            // with both tiles' packs interleaved between stages.
            // Masks (m137): VALU=0x2, MFMA=0x8, DS_READ=0x100.
            SGB(0x100, 9, 0);   // a1,a2lo,a2hi,a3lo,a3hi + 4x bc
            SGB(0x8,   2, 0);   // L1-A, L1-B
            SGB(0x2,  32, 0);   // L1 packs A+B (16 cvt + 16 pk_max)
            SGB(0x8,   4, 0);   // L2 lo/hi x A/B
            SGB(0x2,  32, 0);   // L2 packs A+B
            SGB(0x8,   4, 0);   // L3 lo/hi x A/B
        }

        // ---- epilogues: Y regs 0-7 = rows {4h..4h+3, 8+4h..+3} = (e,o); b3 already inside
        #pragma unroll
        for (int u = 0; u < TB_; ++u) {
            const int tile = tbase + u;
            float p0 = wA[u]*Y[u][0] + wB[u]*Y[u][2] + wC[u]*Y[u][4] + wD[u]*Y[u][6];
            float p1 = wA[u]*Y[u][1] + wB[u]*Y[u][3] + wC[u]*Y[u][5] + wD[u]*Y[u][7];
            p0 += __shfl_xor(p0, 32);
            p1 += __shfl_xor(p1, 32);
            const bool tok = tile < nTiles && ((size_t)tile * 32 + m) < (size_t)nTok;
            if (h == 0 && tok) {
                float2_t ov = {p0 * rs[u], p1 * rs[u]};
                *(float2_t*)(out + ((size_t)tile * 32 + m) * 2) = ov;
            }
        }
    }
}

extern "C" void kernel_launch(void* const* d_in, const int* in_sizes, int n_in,
                              void* d_out, int out_size, void* d_ws, size_t ws_size,
                              hipStream_t stream) {
    const float* x   = (const float*)d_in[0];
    const float* W1  = (const float*)d_in[1];
    const float* b1  = (const float*)d_in[2];
    const float* W2  = (const float*)d_in[3];
    const float* b2  = (const float*)d_in[4];
    const float* W3  = (const float*)d_in[5];
    const float* b3  = (const float*)d_in[6];
    const float* Wg1 = (const float*)d_in[7];
    const float* bg1 = (const float*)d_in[8];
    const float* Wg2 = (const float*)d_in[9];
    const float* bg2 = (const float*)d_in[10];
    float* out = (float*)d_out;

    const int B      = in_sizes[0] / DIN_;
    const int nTiles = (B + 31) / 32;
    // waves_per_eu(2,2): 128 arch + 128 acc (proven). 512 blocks x 4 waves = 2048 waves =
    // exact 2 waves/SIMD; ~45 KB LDS x 2 blocks/CU <= 160 KB. 32768 tiles / 2048 waves =
    // 16 tiles/wave = 8 iterations of 2, zero tail at B=1M.
    const int blocks = 512;
    const int wavesTotal = blocks * 4;
    const int tpw = (nTiles + wavesTotal - 1) / wavesTotal;

    moe_kernel<<<blocks, 256, 0, stream>>>(x, W1, b1, W2, b2, W3, b3,
                                           Wg1, bg1, Wg2, bg2, out, B, nTiles, tpw);
}